// Round 13
// baseline (264.547 us; speedup 1.0000x reference)
//
#include <hip/hip_runtime.h>

#define T_LEN 4096
#define D_IN 128
#define U_H 256
#define REC_MAXV 0.0625f

typedef __attribute__((ext_vector_type(4))) float f32x4;
typedef __attribute__((ext_vector_type(16))) float f32x16;
typedef __attribute__((ext_vector_type(2))) int int2v;
typedef long long i64;

template <bool HI>
__device__ __forceinline__ int pk8(float a, float b, int old) {
    return __builtin_amdgcn_cvt_pk_fp8_f32(a, b, old, HI);
}

__device__ __forceinline__ int reord32(int u) {
    int r = u & 31;
    return ((u >> 5) << 5) + (((r >> 2) & 1) << 4) + ((r >> 3) << 2) + (r & 3);
}

// -------- kernel 0 (fused prep): h, budR, boR, fp8 weight frags, loss0 -------
__global__ void k_pre(const float* __restrict__ xs, const float* __restrict__ We,
                      const float* __restrict__ be, const float* __restrict__ Wd,
                      const float* __restrict__ bd, const float* __restrict__ ud,
                      const float* __restrict__ Wo, const float* __restrict__ bo,
                      float* __restrict__ budR, float* __restrict__ boR,
                      char* __restrict__ WF8, float* __restrict__ part2) {
    __shared__ __align__(16) float hL[256];
    __shared__ float red[2];
    const int b = blockIdx.x, u = threadIdx.x;

    const f32x4* xr = (const f32x4*)(xs + ((size_t)b * T_LEN + (T_LEN - 1)) * D_IN);
    const f32x4* wr = (const f32x4*)(We + (size_t)u * D_IN);
    float s = 0.f;
#pragma unroll
    for (int i = 0; i < 32; ++i) {
        f32x4 a = xr[i], w = wr[i];
        s += a[0]*w[0] + a[1]*w[1] + a[2]*w[2] + a[3]*w[3];
    }
    s += be[u];
    s = fmaxf(s, 0.f);
    hL[u] = s;

    float udc = fminf(fmaxf(ud[u], -REC_MAXV), REC_MAXV);
    budR[(b << 8) + reord32(u)] = bd[u] + udc * s;

    if (b == 0 && u < 128) boR[reord32(u)] = bo[u];

    int gid = b * 256 + u;
    if (gid < 4096) {
        int f = gid >> 6, l = gid & 63;
        int ut = f >> 3, ks = f & 7;
        const float* src = Wd + (size_t)(ut * 32 + (l & 31)) * D_IN + ks * 16 + (l >> 5) * 8;
        int lo = pk8<false>(src[0], src[1], 0); lo = pk8<true>(src[2], src[3], lo);
        int hh = pk8<false>(src[4], src[5], 0); hh = pk8<true>(src[6], src[7], hh);
        *(int2v*)(WF8 + (size_t)gid * 8) = (int2v){lo, hh};
    } else if (gid < 8192) {
        int g = gid - 4096;
        int f = g >> 6, l = g & 63;
        int uk = f >> 2, dt = f & 3;
        const float* src = Wo + (size_t)(dt * 32 + (l & 31)) * U_H + uk * 16 + (l >> 5) * 8;
        int lo = pk8<false>(src[0], src[1], 0); lo = pk8<true>(src[2], src[3], lo);
        int hh = pk8<false>(src[4], src[5], 0); hh = pk8<true>(src[6], src[7], hh);
        *(int2v*)(WF8 + 32768 + (size_t)g * 8) = (int2v){lo, hh};
    }
    __syncthreads();

    float v = 0.f;
    if (u < 128) {
        const f32x4* hr = (const f32x4*)hL;
        const f32x4* wo = (const f32x4*)(Wo + (size_t)u * U_H);
        float s2 = 0.f;
#pragma unroll
        for (int i = 0; i < 64; ++i) {
            f32x4 a = hr[i], w = wo[i];
            s2 += a[0]*w[0] + a[1]*w[1] + a[2]*w[2] + a[3]*w[3];
        }
        s2 += bo[u];
        float x = xs[((size_t)b * T_LEN + T_LEN - 1) * D_IN + u];
        float diff = x - s2;
        v = diff * diff;
    }
#pragma unroll
    for (int o = 32; o > 0; o >>= 1) v += __shfl_down(v, o);
    if (u == 0) red[0] = v;
    if (u == 64) red[1] = v;
    __syncthreads();
    if (u == 0) part2[b] = red[0] + red[1];
}

// ---- phase-1 step for one ut: GEMM1 (2x4 MFMA chains) + bias/relu + pack ----
__device__ __forceinline__ void ph1(const char* lds, const float* budL,
                                    int lane, int hi, int ut,
                                    i64 x0, i64 x1, i64 x2, i64 x3,
                                    i64 x4, i64 x5, i64 x6, i64 x7,
                                    i64& dlo, i64& dhi) {
    f32x16 ca, cb;
#pragma unroll
    for (int i = 0; i < 16; ++i) { ca[i] = 0.f; cb[i] = 0.f; }
    const int base = (ut * 8) << 9;
    ca = __builtin_amdgcn_mfma_f32_32x32x16_fp8_fp8(*(const i64*)(lds + base + (0<<9) + (lane<<3)), x0, ca, 0,0,0);
    cb = __builtin_amdgcn_mfma_f32_32x32x16_fp8_fp8(*(const i64*)(lds + base + (1<<9) + (lane<<3)), x1, cb, 0,0,0);
    ca = __builtin_amdgcn_mfma_f32_32x32x16_fp8_fp8(*(const i64*)(lds + base + (2<<9) + (lane<<3)), x2, ca, 0,0,0);
    cb = __builtin_amdgcn_mfma_f32_32x32x16_fp8_fp8(*(const i64*)(lds + base + (3<<9) + (lane<<3)), x3, cb, 0,0,0);
    ca = __builtin_amdgcn_mfma_f32_32x32x16_fp8_fp8(*(const i64*)(lds + base + (4<<9) + (lane<<3)), x4, ca, 0,0,0);
    cb = __builtin_amdgcn_mfma_f32_32x32x16_fp8_fp8(*(const i64*)(lds + base + (5<<9) + (lane<<3)), x5, cb, 0,0,0);
    ca = __builtin_amdgcn_mfma_f32_32x32x16_fp8_fp8(*(const i64*)(lds + base + (6<<9) + (lane<<3)), x6, ca, 0,0,0);
    cb = __builtin_amdgcn_mfma_f32_32x32x16_fp8_fp8(*(const i64*)(lds + base + (7<<9) + (lane<<3)), x7, cb, 0,0,0);
    const float* bp = budL + ut * 32 + hi * 16;
    f32x16 c;
#pragma unroll
    for (int q = 0; q < 4; ++q) {
        f32x4 bq = *(const f32x4*)(bp + q * 4);
#pragma unroll
        for (int j = 0; j < 4; ++j)
            c[q * 4 + j] = fmaxf(ca[q * 4 + j] + cb[q * 4 + j] + bq[j], 0.f);
    }
    int d0 = pk8<false>(c[0],  c[1],  0); d0 = pk8<true>(c[2],  c[3],  d0);
    int d1 = pk8<false>(c[4],  c[5],  0); d1 = pk8<true>(c[6],  c[7],  d1);
    int d2 = pk8<false>(c[8],  c[9],  0); d2 = pk8<true>(c[10], c[11], d2);
    int d3 = pk8<false>(c[12], c[13], 0); d3 = pk8<true>(c[14], c[15], d3);
    int2v s = __builtin_amdgcn_permlane32_swap(d0, d1, false, false);
    int2v t = __builtin_amdgcn_permlane32_swap(d2, d3, false, false);
    dlo = __builtin_bit_cast(i64, s);
    dhi = __builtin_bit_cast(i64, t);
}

// ---- phase-2 step for one uk: 2 MFMAs into oA/oB ----------------------------
__device__ __forceinline__ void ph2(const char* lds, int lane, int dc, int uk,
                                    i64 db, f32x16& oA, f32x16& oB) {
    i64 w0 = *(const i64*)(lds + 32768 + ((uk * 4 + dc * 2 + 0) << 9) + (lane << 3));
    i64 w1 = *(const i64*)(lds + 32768 + ((uk * 4 + dc * 2 + 1) << 9) + (lane << 3));
    oA = __builtin_amdgcn_mfma_f32_32x32x16_fp8_fp8(w0, db, oA, 0, 0, 0);
    oB = __builtin_amdgcn_mfma_f32_32x32x16_fp8_fp8(w1, db, oB, 0, 0, 0);
}

// ---------------- kernel 1: main pipeline, 4 tiles/wave, in-wave prefetch ----
// 512 blocks x 256 threads (4 waves). Wave handles 4 consecutive 32-row tiles;
// the NEXT tile's 16 global X-loads are issued right after the current tile's
// raw X is converted to fp8 (registers freed), so HBM latency+BW hides under
// the current tile's ph1+ph2+epilogue compute (in-wave load/compute overlap --
// the piece missing from R8-R12, which were occupancy/LDS-insensitive).
__global__ __launch_bounds__(256, 2) void k_main(
        const float* __restrict__ xs, const float* __restrict__ budR,
        const float* __restrict__ boR, const char* __restrict__ WF8,
        float* __restrict__ part) {
    __shared__ __align__(16) char lds[67200];
    const int tid = threadIdx.x;

    for (int i = tid; i < 4096; i += 256)
        ((f32x4*)lds)[i] = ((const f32x4*)WF8)[i];
    const int b = blockIdx.x >> 3;          // 8 blocks per batch-entry
    if (tid < 64) ((f32x4*)(lds + 65536))[tid] = ((const f32x4*)(budR + b * 256))[tid];
    else if (tid < 96) ((f32x4*)(lds + 66560))[tid - 64] = ((const f32x4*)boR)[tid - 64];
    __syncthreads();

    const int wave = tid >> 6, lane = tid & 63;
    const int m = lane & 31, hi = lane >> 5;
    const float* xsb = xs + ((size_t)b << 19);
    const float* budL = (const float*)(lds + 65536);
    const float* boL  = (const float*)(lds + 66560);
    float* wsumf = (float*)(lds + 67072);

    const int tbase = (blockIdx.x * 4 + wave) * 4;   // first of 4 tiles (same b)
    float lacc = 0.f;

    f32x4 rv0, rv1, rv2, rv3, rv4, rv5, rv6, rv7;
    f32x4 rv8, rv9, rv10, rv11, rv12, rv13, rv14, rv15;

#define LOADALL(T0)                                                       \
    {   const float* p = xsb + (size_t)((T0) + m) * 128 + hi * 8;         \
        rv0  = *(const f32x4*)(p +   0); rv1  = *(const f32x4*)(p +   4); \
        rv2  = *(const f32x4*)(p +  16); rv3  = *(const f32x4*)(p +  20); \
        rv4  = *(const f32x4*)(p +  32); rv5  = *(const f32x4*)(p +  36); \
        rv6  = *(const f32x4*)(p +  48); rv7  = *(const f32x4*)(p +  52); \
        rv8  = *(const f32x4*)(p +  64); rv9  = *(const f32x4*)(p +  68); \
        rv10 = *(const f32x4*)(p +  80); rv11 = *(const f32x4*)(p +  84); \
        rv12 = *(const f32x4*)(p +  96); rv13 = *(const f32x4*)(p + 100); \
        rv14 = *(const f32x4*)(p + 112); rv15 = *(const f32x4*)(p + 116); }

#define CV(V0, V1, XV)                                                    \
    {   int lo = pk8<false>(V0[0], V0[1], 0); lo = pk8<true>(V0[2], V0[3], lo); \
        int hh = pk8<false>(V1[0], V1[1], 0); hh = pk8<true>(V1[2], V1[3], hh); \
        XV = __builtin_bit_cast(i64, (int2v){lo, hh}); }

#define STEP(S)                                                           \
    {   const int t0 = ((tbase + (S)) & 127) << 5;                        \
        i64 x0, x1, x2, x3, x4, x5, x6, x7;                               \
        CV(rv0,  rv1,  x0) CV(rv2,  rv3,  x1) CV(rv4,  rv5,  x2)          \
        CV(rv6,  rv7,  x3) CV(rv8,  rv9,  x4) CV(rv10, rv11, x5)          \
        CV(rv12, rv13, x6) CV(rv14, rv15, x7)                             \
        if ((S) < 3) LOADALL(((tbase + (S) + 1) & 127) << 5);             \
        i64 d0a, d0b, d1a, d1b, d2a, d2b, d3a, d3b;                       \
        i64 d4a, d4b, d5a, d5b, d6a, d6b, d7a, d7b;                       \
        ph1(lds, budL, lane, hi, 0, x0,x1,x2,x3,x4,x5,x6,x7, d0a, d0b);   \
        ph1(lds, budL, lane, hi, 1, x0,x1,x2,x3,x4,x5,x6,x7, d1a, d1b);   \
        ph1(lds, budL, lane, hi, 2, x0,x1,x2,x3,x4,x5,x6,x7, d2a, d2b);   \
        ph1(lds, budL, lane, hi, 3, x0,x1,x2,x3,x4,x5,x6,x7, d3a, d3b);   \
        ph1(lds, budL, lane, hi, 4, x0,x1,x2,x3,x4,x5,x6,x7, d4a, d4b);   \
        ph1(lds, budL, lane, hi, 5, x0,x1,x2,x3,x4,x5,x6,x7, d5a, d5b);   \
        ph1(lds, budL, lane, hi, 6, x0,x1,x2,x3,x4,x5,x6,x7, d6a, d6b);   \
        ph1(lds, budL, lane, hi, 7, x0,x1,x2,x3,x4,x5,x6,x7, d7a, d7b);   \
        const int t = t0 + m;                                             \
        const float sel = (t > 0) ? 1.f : 0.f;                            \
        const float* trow = xsb + (size_t)((t > 0) ? t - 1 : 0) * 128;    \
        _Pragma("unroll")                                                 \
        for (int dc = 0; dc < 2; ++dc) {                                  \
            f32x16 o0a, o0b, o1a, o1b;                                    \
            _Pragma("unroll")                                             \
            for (int i = 0; i < 16; ++i)                                  \
                { o0a[i] = 0.f; o0b[i] = 0.f; o1a[i] = 0.f; o1b[i] = 0.f; } \
            ph2(lds, lane, dc,  0, d0a, o0a, o1a);                        \
            ph2(lds, lane, dc,  1, d0b, o0b, o1b);                        \
            ph2(lds, lane, dc,  2, d1a, o0a, o1a);                        \
            ph2(lds, lane, dc,  3, d1b, o0b, o1b);                        \
            ph2(lds, lane, dc,  4, d2a, o0a, o1a);                        \
            ph2(lds, lane, dc,  5, d2b, o0b, o1b);                        \
            ph2(lds, lane, dc,  6, d3a, o0a, o1a);                        \
            ph2(lds, lane, dc,  7, d3b, o0b, o1b);                        \
            ph2(lds, lane, dc,  8, d4a, o0a, o1a);                        \
            ph2(lds, lane, dc,  9, d4b, o0b, o1b);                        \
            ph2(lds, lane, dc, 10, d5a, o0a, o1a);                        \
            ph2(lds, lane, dc, 11, d5b, o0b, o1b);                        \
            ph2(lds, lane, dc, 12, d6a, o0a, o1a);                        \
            ph2(lds, lane, dc, 13, d6b, o0b, o1b);                        \
            ph2(lds, lane, dc, 14, d7a, o0a, o1a);                        \
            ph2(lds, lane, dc, 15, d7b, o0b, o1b);                        \
            _Pragma("unroll")                                             \
            for (int half = 0; half < 2; ++half) {                        \
                const int dt = dc * 2 + half;                             \
                _Pragma("unroll")                                         \
                for (int q = 0; q < 4; ++q) {                             \
                    f32x4 bv = *(const f32x4*)(boL + dt * 32 + hi * 16 + q * 4); \
                    f32x4 tg = *(const f32x4*)(trow + dt * 32 + q * 8 + hi * 4); \
                    _Pragma("unroll")                                     \
                    for (int j = 0; j < 4; ++j) {                         \
                        float ov = (half ? o1a[q * 4 + j] + o1b[q * 4 + j]       \
                                         : o0a[q * 4 + j] + o0b[q * 4 + j]) + bv[j]; \
                        float diff = tg[j] - ov;                          \
                        lacc += sel * diff * diff;                        \
                    }                                                     \
                }                                                         \
            }                                                             \
        }                                                                 \
    }

    LOADALL((tbase & 127) << 5);
    STEP(0)
    STEP(1)
    STEP(2)
    STEP(3)
#undef STEP
#undef CV
#undef LOADALL

    // ---- block-level reduction: ONE store per block, no atomic ----
#pragma unroll
    for (int o = 32; o > 0; o >>= 1) lacc += __shfl_down(lacc, o);
    if (lane == 0) wsumf[wave] = lacc;
    __syncthreads();
    if (tid == 0) {
        float s = 0.f;
#pragma unroll
        for (int i = 0; i < 4; ++i) s += wsumf[i];
        part[blockIdx.x] = s;
    }
}

// ---------------- kernel 2: final reduction (plain store, no atomic) ---------
__global__ void k_final(const float* __restrict__ part, const float* __restrict__ part2,
                        float* __restrict__ loss) {
    __shared__ float ws[16];
    const int tid = threadIdx.x;   // 1024
    float v = (tid < 512) ? part[tid] : 0.f;
    if (tid < 64) v += part2[tid];
#pragma unroll
    for (int o = 32; o > 0; o >>= 1) v += __shfl_down(v, o);
    if ((tid & 63) == 0) ws[tid >> 6] = v;
    __syncthreads();
    if (tid == 0) {
        float s = 0.f;
#pragma unroll
        for (int i = 0; i < 16; ++i) s += ws[i];
        *loss = s * (1.f / 262144.f);
    }
}

extern "C" void kernel_launch(void* const* d_in, const int* in_sizes, int n_in,
                              void* d_out, int out_size, void* d_ws, size_t ws_size,
                              hipStream_t stream) {
    const float* xs = (const float*)d_in[0];
    const float* We = (const float*)d_in[1];
    const float* be = (const float*)d_in[2];
    // d_in[3] = ue (unused: encoder hidden state is always zero)
    const float* Wd = (const float*)d_in[4];
    const float* bd = (const float*)d_in[5];
    const float* ud = (const float*)d_in[6];
    const float* Wo = (const float*)d_in[7];
    const float* bo = (const float*)d_in[8];
    float* loss = (float*)d_out;

    char* ws = (char*)d_ws;
    float* budR  = (float*)(ws);             // 65536 B
    char*  WF8   = (char*)(ws + 65536);      // 65536 B (Wd frags, then Wo frags)
    float* boR   = (float*)(ws + 131072);    // 512 B
    float* part  = (float*)(ws + 131584);    // 2048 B (512 block partials)
    float* part2 = (float*)(ws + 133632);    // 256 B  (64 loss0 partials)

    k_pre<<<64, 256, 0, stream>>>(xs, We, be, Wd, bd, ud, Wo, bo,
                                  budR, boR, WF8, part2);
    k_main<<<512, 256, 0, stream>>>(xs, budR, boR, WF8, part);
    k_final<<<1, 1024, 0, stream>>>(part, part2, loss);
}

// Round 14
// 68.678 us; speedup vs baseline: 3.8520x; 3.8520x over previous
//
#include <hip/hip_runtime.h>

#define T_LEN 4096
#define D_IN 128
#define U_H 256
#define REC_MAXV 0.0625f

typedef __attribute__((ext_vector_type(4))) float f32x4;
typedef __attribute__((ext_vector_type(16))) float f32x16;
typedef __attribute__((ext_vector_type(2))) int int2v;
typedef long long i64;

template <bool HI>
__device__ __forceinline__ int pk8(float a, float b, int old) {
    return __builtin_amdgcn_cvt_pk_fp8_f32(a, b, old, HI);
}

__device__ __forceinline__ int reord32(int u) {
    int r = u & 31;
    return ((u >> 5) << 5) + (((r >> 2) & 1) << 4) + ((r >> 3) << 2) + (r & 3);
}

// -------- kernel 0 (fused prep): h, budR, boR, fp8 weight frags, loss0 -------
__global__ void k_pre(const float* __restrict__ xs, const float* __restrict__ We,
                      const float* __restrict__ be, const float* __restrict__ Wd,
                      const float* __restrict__ bd, const float* __restrict__ ud,
                      const float* __restrict__ Wo, const float* __restrict__ bo,
                      float* __restrict__ budR, float* __restrict__ boR,
                      char* __restrict__ WF8, float* __restrict__ part2) {
    __shared__ __align__(16) float hL[256];
    __shared__ float red[2];
    const int b = blockIdx.x, u = threadIdx.x;

    const f32x4* xr = (const f32x4*)(xs + ((size_t)b * T_LEN + (T_LEN - 1)) * D_IN);
    const f32x4* wr = (const f32x4*)(We + (size_t)u * D_IN);
    float s = 0.f;
#pragma unroll
    for (int i = 0; i < 32; ++i) {
        f32x4 a = xr[i], w = wr[i];
        s += a[0]*w[0] + a[1]*w[1] + a[2]*w[2] + a[3]*w[3];
    }
    s += be[u];
    s = fmaxf(s, 0.f);
    hL[u] = s;

    float udc = fminf(fmaxf(ud[u], -REC_MAXV), REC_MAXV);
    budR[(b << 8) + reord32(u)] = bd[u] + udc * s;

    if (b == 0 && u < 128) boR[reord32(u)] = bo[u];

    int gid = b * 256 + u;
    if (gid < 4096) {
        int f = gid >> 6, l = gid & 63;
        int ut = f >> 3, ks = f & 7;
        const float* src = Wd + (size_t)(ut * 32 + (l & 31)) * D_IN + ks * 16 + (l >> 5) * 8;
        int lo = pk8<false>(src[0], src[1], 0); lo = pk8<true>(src[2], src[3], lo);
        int hh = pk8<false>(src[4], src[5], 0); hh = pk8<true>(src[6], src[7], hh);
        *(int2v*)(WF8 + (size_t)gid * 8) = (int2v){lo, hh};
    } else if (gid < 8192) {
        int g = gid - 4096;
        int f = g >> 6, l = g & 63;
        int uk = f >> 2, dt = f & 3;
        const float* src = Wo + (size_t)(dt * 32 + (l & 31)) * U_H + uk * 16 + (l >> 5) * 8;
        int lo = pk8<false>(src[0], src[1], 0); lo = pk8<true>(src[2], src[3], lo);
        int hh = pk8<false>(src[4], src[5], 0); hh = pk8<true>(src[6], src[7], hh);
        *(int2v*)(WF8 + 32768 + (size_t)g * 8) = (int2v){lo, hh};
    }
    __syncthreads();

    float v = 0.f;
    if (u < 128) {
        const f32x4* hr = (const f32x4*)hL;
        const f32x4* wo = (const f32x4*)(Wo + (size_t)u * U_H);
        float s2 = 0.f;
#pragma unroll
        for (int i = 0; i < 64; ++i) {
            f32x4 a = hr[i], w = wo[i];
            s2 += a[0]*w[0] + a[1]*w[1] + a[2]*w[2] + a[3]*w[3];
        }
        s2 += bo[u];
        float x = xs[((size_t)b * T_LEN + T_LEN - 1) * D_IN + u];
        float diff = x - s2;
        v = diff * diff;
    }
#pragma unroll
    for (int o = 32; o > 0; o >>= 1) v += __shfl_down(v, o);
    if (u == 0) red[0] = v;
    if (u == 64) red[1] = v;
    __syncthreads();
    if (u == 0) part2[b] = red[0] + red[1];
}

// ---- phase-1 step for one ut: GEMM1 (2x4 MFMA chains) + bias/relu + pack ----
__device__ __forceinline__ void ph1(const char* lds, const float* budL,
                                    int lane, int hi, int ut,
                                    i64 x0, i64 x1, i64 x2, i64 x3,
                                    i64 x4, i64 x5, i64 x6, i64 x7,
                                    i64& dlo, i64& dhi) {
    f32x16 ca, cb;
#pragma unroll
    for (int i = 0; i < 16; ++i) { ca[i] = 0.f; cb[i] = 0.f; }
    const int base = (ut * 8) << 9;
    ca = __builtin_amdgcn_mfma_f32_32x32x16_fp8_fp8(*(const i64*)(lds + base + (0<<9) + (lane<<3)), x0, ca, 0,0,0);
    cb = __builtin_amdgcn_mfma_f32_32x32x16_fp8_fp8(*(const i64*)(lds + base + (1<<9) + (lane<<3)), x1, cb, 0,0,0);
    ca = __builtin_amdgcn_mfma_f32_32x32x16_fp8_fp8(*(const i64*)(lds + base + (2<<9) + (lane<<3)), x2, ca, 0,0,0);
    cb = __builtin_amdgcn_mfma_f32_32x32x16_fp8_fp8(*(const i64*)(lds + base + (3<<9) + (lane<<3)), x3, cb, 0,0,0);
    ca = __builtin_amdgcn_mfma_f32_32x32x16_fp8_fp8(*(const i64*)(lds + base + (4<<9) + (lane<<3)), x4, ca, 0,0,0);
    cb = __builtin_amdgcn_mfma_f32_32x32x16_fp8_fp8(*(const i64*)(lds + base + (5<<9) + (lane<<3)), x5, cb, 0,0,0);
    ca = __builtin_amdgcn_mfma_f32_32x32x16_fp8_fp8(*(const i64*)(lds + base + (6<<9) + (lane<<3)), x6, ca, 0,0,0);
    cb = __builtin_amdgcn_mfma_f32_32x32x16_fp8_fp8(*(const i64*)(lds + base + (7<<9) + (lane<<3)), x7, cb, 0,0,0);
    const float* bp = budL + ut * 32 + hi * 16;
    f32x16 c;
#pragma unroll
    for (int q = 0; q < 4; ++q) {
        f32x4 bq = *(const f32x4*)(bp + q * 4);
#pragma unroll
        for (int j = 0; j < 4; ++j)
            c[q * 4 + j] = fmaxf(ca[q * 4 + j] + cb[q * 4 + j] + bq[j], 0.f);
    }
    int d0 = pk8<false>(c[0],  c[1],  0); d0 = pk8<true>(c[2],  c[3],  d0);
    int d1 = pk8<false>(c[4],  c[5],  0); d1 = pk8<true>(c[6],  c[7],  d1);
    int d2 = pk8<false>(c[8],  c[9],  0); d2 = pk8<true>(c[10], c[11], d2);
    int d3 = pk8<false>(c[12], c[13], 0); d3 = pk8<true>(c[14], c[15], d3);
    int2v s = __builtin_amdgcn_permlane32_swap(d0, d1, false, false);
    int2v t = __builtin_amdgcn_permlane32_swap(d2, d3, false, false);
    dlo = __builtin_bit_cast(i64, s);
    dhi = __builtin_bit_cast(i64, t);
    __builtin_amdgcn_sched_barrier(0);
}

// ---- phase-2 step for one uk: 2 MFMAs into oA/oB ----------------------------
__device__ __forceinline__ void ph2(const char* lds, int lane, int dc, int uk,
                                    i64 db, f32x16& oA, f32x16& oB) {
    i64 w0 = *(const i64*)(lds + 32768 + ((uk * 4 + dc * 2 + 0) << 9) + (lane << 3));
    i64 w1 = *(const i64*)(lds + 32768 + ((uk * 4 + dc * 2 + 1) << 9) + (lane << 3));
    oA = __builtin_amdgcn_mfma_f32_32x32x16_fp8_fp8(w0, db, oA, 0, 0, 0);
    oB = __builtin_amdgcn_mfma_f32_32x32x16_fp8_fp8(w1, db, oB, 0, 0, 0);
}

// ---------------- kernel 1: main pipeline, 2 tiles/wave, chunked prefetch ----
// 512 blocks x 512 threads (8 waves). Wave = 2 consecutive 32-row tiles.
// Tile B's X is prefetched in 2-chunk flights (16 VGPR max) during tile A's
// ph1 phases, converted to fp8 two phases after issue (~600cy cover). Tile B's
// HBM time hides under tile A's compute -- in-wave overlap at R10's register
// discipline (R13's 64-VGPR burst prefetch spilled; this caps flight regs).
__global__ __launch_bounds__(512, 2) void k_main(
        const float* __restrict__ xs, const float* __restrict__ budR,
        const float* __restrict__ boR, const char* __restrict__ WF8,
        float* __restrict__ part) {
    __shared__ __align__(16) char lds[67200];
    const int tid = threadIdx.x;

    for (int i = tid; i < 4096; i += 512)
        ((f32x4*)lds)[i] = ((const f32x4*)WF8)[i];
    const int b = blockIdx.x >> 3;          // 8 blocks per batch-entry
    if (tid < 64) ((f32x4*)(lds + 65536))[tid] = ((const f32x4*)(budR + b * 256))[tid];
    else if (tid < 96) ((f32x4*)(lds + 66560))[tid - 64] = ((const f32x4*)boR)[tid - 64];
    __syncthreads();

    const int wave = tid >> 6, lane = tid & 63;
    const int m = lane & 31, hi = lane >> 5;
    const float* xsb = xs + ((size_t)b << 19);
    const float* budL = (const float*)(lds + 65536);
    const float* boL  = (const float*)(lds + 66560);
    float* wsumf = (float*)(lds + 67072);

    const int tile0 = blockIdx.x * 16 + wave * 2;   // even; tileB = tile0+1
    const int t0A = (tile0 & 127) << 5;
    const int t0B = ((tile0 + 1) & 127) << 5;
    float lacc = 0.f;

#define CVP(V0, V1) __extension__({                                       \
        int lo_ = pk8<false>((V0)[0], (V0)[1], 0);                        \
        lo_ = pk8<true>((V0)[2], (V0)[3], lo_);                           \
        int hh_ = pk8<false>((V1)[0], (V1)[1], 0);                        \
        hh_ = pk8<true>((V1)[2], (V1)[3], hh_);                           \
        __builtin_bit_cast(i64, (int2v){lo_, hh_}); })

    // ---- tile A: X -> fp8 (immediate convert, R10 pattern) ----
    i64 x0, x1, x2, x3, x4, x5, x6, x7;
    {
        const float* p = xsb + (size_t)(t0A + m) * 128 + hi * 8;
        { f32x4 v0 = *(const f32x4*)(p +   0), v1 = *(const f32x4*)(p +   4); x0 = CVP(v0, v1); }
        { f32x4 v0 = *(const f32x4*)(p +  16), v1 = *(const f32x4*)(p +  20); x1 = CVP(v0, v1); }
        { f32x4 v0 = *(const f32x4*)(p +  32), v1 = *(const f32x4*)(p +  36); x2 = CVP(v0, v1); }
        { f32x4 v0 = *(const f32x4*)(p +  48), v1 = *(const f32x4*)(p +  52); x3 = CVP(v0, v1); }
        { f32x4 v0 = *(const f32x4*)(p +  64), v1 = *(const f32x4*)(p +  68); x4 = CVP(v0, v1); }
        { f32x4 v0 = *(const f32x4*)(p +  80), v1 = *(const f32x4*)(p +  84); x5 = CVP(v0, v1); }
        { f32x4 v0 = *(const f32x4*)(p +  96), v1 = *(const f32x4*)(p + 100); x6 = CVP(v0, v1); }
        { f32x4 v0 = *(const f32x4*)(p + 112), v1 = *(const f32x4*)(p + 116); x7 = CVP(v0, v1); }
    }

    // ---- tile A ph1, interleaved with tile B chunked prefetch ----
    const float* pN = xsb + (size_t)(t0B + m) * 128 + hi * 8;
    i64 y0, y1, y2, y3, y4, y5, y6, y7;
    i64 dA0a, dA0b, dA1a, dA1b, dA2a, dA2b, dA3a, dA3b;
    i64 dA4a, dA4b, dA5a, dA5b, dA6a, dA6b, dA7a, dA7b;
    {
        f32x4 pa0, pa1, pb0, pb1;
        pa0 = *(const f32x4*)(pN +  0); pa1 = *(const f32x4*)(pN +  4);
        pb0 = *(const f32x4*)(pN + 16); pb1 = *(const f32x4*)(pN + 20);
        ph1(lds, budL, lane, hi, 0, x0,x1,x2,x3,x4,x5,x6,x7, dA0a, dA0b);
        y0 = CVP(pa0, pa1);
        pa0 = *(const f32x4*)(pN + 32); pa1 = *(const f32x4*)(pN + 36);
        ph1(lds, budL, lane, hi, 1, x0,x1,x2,x3,x4,x5,x6,x7, dA1a, dA1b);
        y1 = CVP(pb0, pb1);
        pb0 = *(const f32x4*)(pN + 48); pb1 = *(const f32x4*)(pN + 52);
        ph1(lds, budL, lane, hi, 2, x0,x1,x2,x3,x4,x5,x6,x7, dA2a, dA2b);
        y2 = CVP(pa0, pa1);
        pa0 = *(const f32x4*)(pN + 64); pa1 = *(const f32x4*)(pN + 68);
        ph1(lds, budL, lane, hi, 3, x0,x1,x2,x3,x4,x5,x6,x7, dA3a, dA3b);
        y3 = CVP(pb0, pb1);
        pb0 = *(const f32x4*)(pN + 80); pb1 = *(const f32x4*)(pN + 84);
        ph1(lds, budL, lane, hi, 4, x0,x1,x2,x3,x4,x5,x6,x7, dA4a, dA4b);
        y4 = CVP(pa0, pa1);
        pa0 = *(const f32x4*)(pN + 96); pa1 = *(const f32x4*)(pN + 100);
        ph1(lds, budL, lane, hi, 5, x0,x1,x2,x3,x4,x5,x6,x7, dA5a, dA5b);
        y5 = CVP(pb0, pb1);
        pb0 = *(const f32x4*)(pN + 112); pb1 = *(const f32x4*)(pN + 116);
        ph1(lds, budL, lane, hi, 6, x0,x1,x2,x3,x4,x5,x6,x7, dA6a, dA6b);
        y6 = CVP(pa0, pa1);
        ph1(lds, budL, lane, hi, 7, x0,x1,x2,x3,x4,x5,x6,x7, dA7a, dA7b);
        y7 = CVP(pb0, pb1);
    }

#define PH2EPI(T0, D0a,D0b,D1a,D1b,D2a,D2b,D3a,D3b,D4a,D4b,D5a,D5b,D6a,D6b,D7a,D7b) \
    {   const int t = (T0) + m;                                           \
        const float sel = (t > 0) ? 1.f : 0.f;                            \
        const float* trow = xsb + (size_t)((t > 0) ? t - 1 : 0) * 128;    \
        _Pragma("unroll")                                                 \
        for (int dc = 0; dc < 2; ++dc) {                                  \
            f32x16 o0a, o0b, o1a, o1b;                                    \
            _Pragma("unroll")                                             \
            for (int i = 0; i < 16; ++i)                                  \
                { o0a[i] = 0.f; o0b[i] = 0.f; o1a[i] = 0.f; o1b[i] = 0.f; } \
            ph2(lds, lane, dc,  0, D0a, o0a, o1a);                        \
            ph2(lds, lane, dc,  1, D0b, o0b, o1b);                        \
            ph2(lds, lane, dc,  2, D1a, o0a, o1a);                        \
            ph2(lds, lane, dc,  3, D1b, o0b, o1b);                        \
            ph2(lds, lane, dc,  4, D2a, o0a, o1a);                        \
            ph2(lds, lane, dc,  5, D2b, o0b, o1b);                        \
            ph2(lds, lane, dc,  6, D3a, o0a, o1a);                        \
            ph2(lds, lane, dc,  7, D3b, o0b, o1b);                        \
            ph2(lds, lane, dc,  8, D4a, o0a, o1a);                        \
            ph2(lds, lane, dc,  9, D4b, o0b, o1b);                        \
            ph2(lds, lane, dc, 10, D5a, o0a, o1a);                        \
            ph2(lds, lane, dc, 11, D5b, o0b, o1b);                        \
            ph2(lds, lane, dc, 12, D6a, o0a, o1a);                        \
            ph2(lds, lane, dc, 13, D6b, o0b, o1b);                        \
            ph2(lds, lane, dc, 14, D7a, o0a, o1a);                        \
            ph2(lds, lane, dc, 15, D7b, o0b, o1b);                        \
            __builtin_amdgcn_sched_barrier(0);                            \
            _Pragma("unroll")                                             \
            for (int half = 0; half < 2; ++half) {                        \
                const int dt = dc * 2 + half;                             \
                _Pragma("unroll")                                         \
                for (int q = 0; q < 4; ++q) {                             \
                    f32x4 bv = *(const f32x4*)(boL + dt * 32 + hi * 16 + q * 4); \
                    f32x4 tg = *(const f32x4*)(trow + dt * 32 + q * 8 + hi * 4); \
                    _Pragma("unroll")                                     \
                    for (int j = 0; j < 4; ++j) {                         \
                        float ov = (half ? o1a[q * 4 + j] + o1b[q * 4 + j]       \
                                         : o0a[q * 4 + j] + o0b[q * 4 + j]) + bv[j]; \
                        float diff = tg[j] - ov;                          \
                        lacc += sel * diff * diff;                        \
                    }                                                     \
                }                                                         \
            }                                                             \
        }                                                                 \
    }

    // ---- tile A ph2 + epilogue (tile B loads still landing under this) ----
    PH2EPI(t0A, dA0a,dA0b,dA1a,dA1b,dA2a,dA2b,dA3a,dA3b,
                dA4a,dA4b,dA5a,dA5b,dA6a,dA6b,dA7a,dA7b)

    // ---- tile B: ph1 (x = y, no prefetch) + ph2 + epilogue ----
    {
        i64 dB0a, dB0b, dB1a, dB1b, dB2a, dB2b, dB3a, dB3b;
        i64 dB4a, dB4b, dB5a, dB5b, dB6a, dB6b, dB7a, dB7b;
        ph1(lds, budL, lane, hi, 0, y0,y1,y2,y3,y4,y5,y6,y7, dB0a, dB0b);
        ph1(lds, budL, lane, hi, 1, y0,y1,y2,y3,y4,y5,y6,y7, dB1a, dB1b);
        ph1(lds, budL, lane, hi, 2, y0,y1,y2,y3,y4,y5,y6,y7, dB2a, dB2b);
        ph1(lds, budL, lane, hi, 3, y0,y1,y2,y3,y4,y5,y6,y7, dB3a, dB3b);
        ph1(lds, budL, lane, hi, 4, y0,y1,y2,y3,y4,y5,y6,y7, dB4a, dB4b);
        ph1(lds, budL, lane, hi, 5, y0,y1,y2,y3,y4,y5,y6,y7, dB5a, dB5b);
        ph1(lds, budL, lane, hi, 6, y0,y1,y2,y3,y4,y5,y6,y7, dB6a, dB6b);
        ph1(lds, budL, lane, hi, 7, y0,y1,y2,y3,y4,y5,y6,y7, dB7a, dB7b);
        PH2EPI(t0B, dB0a,dB0b,dB1a,dB1b,dB2a,dB2b,dB3a,dB3b,
                    dB4a,dB4b,dB5a,dB5b,dB6a,dB6b,dB7a,dB7b)
    }
#undef PH2EPI
#undef CVP

    // ---- block-level reduction: ONE store per block, no atomic ----
#pragma unroll
    for (int o = 32; o > 0; o >>= 1) lacc += __shfl_down(lacc, o);
    if (lane == 0) wsumf[wave] = lacc;
    __syncthreads();
    if (tid == 0) {
        float s = 0.f;
#pragma unroll
        for (int i = 0; i < 8; ++i) s += wsumf[i];
        part[blockIdx.x] = s;
    }
}

// ---------------- kernel 2: final reduction (plain store, no atomic) ---------
__global__ void k_final(const float* __restrict__ part, const float* __restrict__ part2,
                        float* __restrict__ loss) {
    __shared__ float ws[16];
    const int tid = threadIdx.x;   // 1024
    float v = (tid < 512) ? part[tid] : 0.f;
    if (tid < 64) v += part2[tid];
#pragma unroll
    for (int o = 32; o > 0; o >>= 1) v += __shfl_down(v, o);
    if ((tid & 63) == 0) ws[tid >> 6] = v;
    __syncthreads();
    if (tid == 0) {
        float s = 0.f;
#pragma unroll
        for (int i = 0; i < 16; ++i) s += ws[i];
        *loss = s * (1.f / 262144.f);
    }
}

extern "C" void kernel_launch(void* const* d_in, const int* in_sizes, int n_in,
                              void* d_out, int out_size, void* d_ws, size_t ws_size,
                              hipStream_t stream) {
    const float* xs = (const float*)d_in[0];
    const float* We = (const float*)d_in[1];
    const float* be = (const float*)d_in[2];
    // d_in[3] = ue (unused: encoder hidden state is always zero)
    const float* Wd = (const float*)d_in[4];
    const float* bd = (const float*)d_in[5];
    const float* ud = (const float*)d_in[6];
    const float* Wo = (const float*)d_in[7];
    const float* bo = (const float*)d_in[8];
    float* loss = (float*)d_out;

    char* ws = (char*)d_ws;
    float* budR  = (float*)(ws);             // 65536 B
    char*  WF8   = (char*)(ws + 65536);      // 65536 B (Wd frags, then Wo frags)
    float* boR   = (float*)(ws + 131072);    // 512 B
    float* part  = (float*)(ws + 131584);    // 2048 B (512 block partials)
    float* part2 = (float*)(ws + 133632);    // 256 B  (64 loss0 partials)

    k_pre<<<64, 256, 0, stream>>>(xs, We, be, Wd, bd, ud, Wo, bo,
                                  budR, boR, WF8, part2);
    k_main<<<512, 512, 0, stream>>>(xs, budR, boR, WF8, part);
    k_final<<<1, 1024, 0, stream>>>(part, part2, loss);
}